// Round 1
// baseline (300.556 us; speedup 1.0000x reference)
//
#include <hip/hip_runtime.h>
#include <cstdint>
#include <cstddef>

// SLAYER SRM-alpha constants, rounded-to-nearest f32 from double
#define THETA_F 10.0f
__device__ __constant__ float c_unused; // keep compiler quiet if needed

#define DS_C 0.9048374180359595731642491f   // exp(-0.1)
#define DR_C 0.3678794411714423215955238f   // exp(-1.0)
#define CS_C 0.2718281828459045235360287f   // e/10
#define CR_C -54.3656365691809047072057f    // -2*10*e

// ---------------------------------------------------------------------------
// K1: layer-1 fc (K=4, binary inputs -> 16-entry table) + psp_spike recursion.
// One thread per (b,h) channel; 2000 serial steps; spikes bit-packed via ballot.
// grid 128 (b = blk>>1, h0 = (blk&1)*256), block 256.
// s1p layout: u64 [64][2000][8]   (bit l of word g = spike of h = g*64+l)
// ---------------------------------------------------------------------------
__global__ __launch_bounds__(256) void k1_layer1(
    const float* __restrict__ inp,                 // [64][4][2000]
    const float* __restrict__ W1,                  // [512][4]
    unsigned long long* __restrict__ s1p)          // [64][2000][8]
{
    __shared__ float table[16 * 256];
    __shared__ unsigned char codes[256];

    const int tid = threadIdx.x;
    const int b  = blockIdx.x >> 1;
    const int h0 = (blockIdx.x & 1) << 8;
    const int h  = h0 + tid;

    const float w0 = W1[h * 4 + 0];
    const float w1 = W1[h * 4 + 1];
    const float w2 = W1[h * 4 + 2];
    const float w3 = W1[h * 4 + 3];
    // table[c] = ((w0*b0 + w1*b1) + w2*b2) + w3*b3 with b_i in {0,1}: bitwise
    // identical to the reference einsum contraction (products with 0/1 exact).
    for (int c = 0; c < 16; ++c) {
        float v = __fmul_rn(w0, (c & 1) ? 1.0f : 0.0f);
        v = __fadd_rn(v, __fmul_rn(w1, (c & 2) ? 1.0f : 0.0f));
        v = __fadd_rn(v, __fmul_rn(w2, (c & 4) ? 1.0f : 0.0f));
        v = __fadd_rn(v, __fmul_rn(w3, (c & 8) ? 1.0f : 0.0f));
        table[c * 256 + tid] = v;
    }

    float xs = 0.0f, ys = 0.0f, xr = 0.0f, yr = 0.0f;
    const int  g      = (h0 >> 6) + (tid >> 6);
    const bool w_lead = (tid & 63) == 0;

    for (int t0 = 0; t0 < 2000; t0 += 250) {
        __syncthreads();                        // protect codes reuse
        if (tid < 250) {
            const int t = t0 + tid;
            const float v0 = inp[(b * 4 + 0) * 2000 + t];
            const float v1 = inp[(b * 4 + 1) * 2000 + t];
            const float v2 = inp[(b * 4 + 2) * 2000 + t];
            const float v3 = inp[(b * 4 + 3) * 2000 + t];
            int c = (int)(v0 != 0.0f) | ((int)(v1 != 0.0f) << 1) |
                    ((int)(v2 != 0.0f) << 2) | ((int)(v3 != 0.0f) << 3);
            codes[tid] = (unsigned char)c;
        }
        __syncthreads();

        for (int k = 0; k < 250; ++k) {
            const float a = table[(int)codes[k] * 256 + tid];
            // membrane from carry state (before consuming a_t / s_t)
            const float u  = __fadd_rn(__fmul_rn(CS_C, ys), __fmul_rn(CR_C, yr));
            const float v  = __fsub_rn(u, THETA_F);
            const bool  sp = (v >= 0.0f);
            const float s  = sp ? 1.0f : 0.0f;
            // state updates, exact reference op order (TS=1 mults elided: exact)
            xs = __fadd_rn(__fmul_rn(DS_C, xs), a);
            ys = __fmul_rn(DS_C, __fadd_rn(ys, xs));
            xr = __fadd_rn(__fmul_rn(DR_C, xr), s);
            yr = __fmul_rn(DR_C, __fadd_rn(yr, xr));

            const unsigned long long m = __ballot(sp);
            if (w_lead) s1p[(size_t)(b * 2000 + t0 + k) * 8 + g] = m;
        }
    }
}

// ---------------------------------------------------------------------------
// K2: a2[b,o,t] = sum_h W2[o,h] * s1[b,h,t]  (ascending h; zero terms skipped
// -- bitwise identical since adding +0.0 is a no-op and accs start at +0).
// One thread per (b,t). Writes a2 rows [b*2+o][2000] into d_out (staging).
// ---------------------------------------------------------------------------
__global__ __launch_bounds__(256) void k2_fc2(
    const unsigned long long* __restrict__ s1p,    // [64][2000][8]
    const float* __restrict__ W2,                  // [2][512]
    float* __restrict__ a2)                        // [128][2000]
{
    __shared__ float w2s[1024];
    const int tid = threadIdx.x;
    for (int j = tid; j < 1024; j += 256) w2s[j] = W2[j];
    __syncthreads();

    const int idx = blockIdx.x * 256 + tid;        // = b*2000 + t, 0..127999
    const unsigned long long* mp = s1p + (size_t)idx * 8;

    float acc0 = 0.0f, acc1 = 0.0f;
    #pragma unroll
    for (int gg = 0; gg < 8; ++gg) {
        unsigned long long m = mp[gg];
        while (m) {
            const int i = __builtin_ctzll(m);
            m &= m - 1;
            const int hh = gg * 64 + i;
            acc0 = __fadd_rn(acc0, w2s[hh]);
            acc1 = __fadd_rn(acc1, w2s[512 + hh]);
        }
    }
    const int b = idx / 2000;
    const int t = idx - b * 2000;
    a2[(size_t)(b * 2 + 0) * 2000 + t] = acc0;
    a2[(size_t)(b * 2 + 1) * 2000 + t] = acc1;
}

// ---------------------------------------------------------------------------
// K3: layer-2 psp_spike + final psp readout, fused. 128 chains (b,o).
// Reads a2 in-place from d_out rows and overwrites with p (read-before-write
// within the same thread). grid 2 x block 64.
// ---------------------------------------------------------------------------
__global__ __launch_bounds__(64) void k3_layer2(float* __restrict__ io)
{
    const int idx = blockIdx.x * 64 + threadIdx.x; // row = b*2+o, 0..127
    float* row = io + (size_t)idx * 2000;

    float xs2 = 0.0f, ys2 = 0.0f, xr2 = 0.0f, yr2 = 0.0f;
    float xs3 = 0.0f, ys3 = 0.0f;

    for (int t = 0; t < 2000; t += 4) {
        const float4 a4 = *reinterpret_cast<const float4*>(row + t);
        float p0, p1, p2, p3;
        float a;
        #pragma unroll
        for (int j = 0; j < 4; ++j) {
            a = (j == 0) ? a4.x : (j == 1) ? a4.y : (j == 2) ? a4.z : a4.w;
            const float u  = __fadd_rn(__fmul_rn(CS_C, ys2), __fmul_rn(CR_C, yr2));
            const float v  = __fsub_rn(u, THETA_F);
            const float s  = (v >= 0.0f) ? 1.0f : 0.0f;
            const float p  = __fmul_rn(CS_C, ys3);   // readout BEFORE consuming s2[t]
            if (j == 0) p0 = p; else if (j == 1) p1 = p; else if (j == 2) p2 = p; else p3 = p;
            // layer-2 neuron state
            xs2 = __fadd_rn(__fmul_rn(DS_C, xs2), a);
            ys2 = __fmul_rn(DS_C, __fadd_rn(ys2, xs2));
            xr2 = __fadd_rn(__fmul_rn(DR_C, xr2), s);
            yr2 = __fmul_rn(DR_C, __fadd_rn(yr2, xr2));
            // readout psp state driven by s2
            xs3 = __fadd_rn(__fmul_rn(DS_C, xs3), s);
            ys3 = __fmul_rn(DS_C, __fadd_rn(ys3, xs3));
        }
        *reinterpret_cast<float4*>(row + t) = make_float4(p0, p1, p2, p3);
    }
}

extern "C" void kernel_launch(void* const* d_in, const int* in_sizes, int n_in,
                              void* d_out, int out_size, void* d_ws, size_t ws_size,
                              hipStream_t stream)
{
    const float* inp = (const float*)d_in[0];  // [64][4][2000]
    const float* W1  = (const float*)d_in[1];  // [512][4]
    const float* W2  = (const float*)d_in[2];  // [2][512]
    float* out = (float*)d_out;                // [64][2][2000]

    unsigned long long* s1p = (unsigned long long*)d_ws;   // 8,192,000 B

    k1_layer1<<<dim3(128), dim3(256), 0, stream>>>(inp, W1, s1p);
    k2_fc2<<<dim3(500), dim3(256), 0, stream>>>(s1p, W2, out);
    k3_layer2<<<dim3(2), dim3(64), 0, stream>>>(out);
}